// Round 17
// baseline (4218.055 us; speedup 1.0000x reference)
//
#include <hip/hip_runtime.h>

typedef _Float16 f16;
typedef __attribute__((ext_vector_type(8))) _Float16 f16x8;
typedef __attribute__((ext_vector_type(16))) float f32x16;
typedef __attribute__((ext_vector_type(2))) unsigned int u32x2;
typedef __attribute__((ext_vector_type(4))) unsigned int u32x4;
typedef unsigned int u32;
typedef unsigned short u16;

#define UNITS 32
#define HID   1024
#define NCH   32      // 32 chunks of 32 j
#define TPB   256     // 4 waves
#define WPB   4
#define SPB   256     // samples per block: 4 waves x 64 (2 tiles of 32)
#define NBLK  512
#define BWDOFF 262144

static_assert(NBLK * SPB == 131072, "grid covers batch");

// d_ws (512 KB): two regions (FWD @0, BWD @256KB), each
// [c:32][load:8][lane:64][16B], load = slice*2 + ks.
// FWD slices: 0/1 = W1^T hi/lo (A of H^T=W1^T@Z^T), 2/3 = W2^T hi/lo (A of Y^T)
// BWD slices: 0/1 = W2  hi/lo (A of GR^T=W2@G^T),   2/3 = W1  hi/lo (A of K^T)
// lo residuals UNSCALED: lo = f16(v - hi); all 3 split MFMAs share one C.
__global__ void prep_weights(const float* __restrict__ W1,
                             const float* __restrict__ W2,
                             f16* __restrict__ ws) {
    int idx = blockIdx.x * 256 + threadIdx.x;   // (c, jl, u)
    int c = idx >> 10, rem = idx & 1023;
    int jl = rem >> 5, u = rem & 31;
    int j = c * 32 + jl;
    float w1 = W1[u * HID + j];
    f16 h1 = (f16)w1;
    f16 l1 = (f16)(w1 - (float)h1);
    float w2 = W2[j * UNITS + u];
    f16 h2 = (f16)w2;
    f16 l2 = (f16)(w2 - (float)h2);
    char* p = (char*)ws;
    auto off = [&](int region, int slice, int row, int k) {
        int ks = k >> 4;
        int lane = row + ((k >> 3) & 1) * 32;
        return region + c * 8192 + (slice * 2 + ks) * 1024 + lane * 16 + (k & 7) * 2;
    };
    *(f16*)(p + off(0, 0, jl, u))      = h1;
    *(f16*)(p + off(0, 1, jl, u))      = l1;
    *(f16*)(p + off(0, 2, u, jl))      = h2;
    *(f16*)(p + off(0, 3, u, jl))      = l2;
    *(f16*)(p + off(BWDOFF, 0, jl, u)) = h2;
    *(f16*)(p + off(BWDOFF, 1, jl, u)) = l2;
    *(f16*)(p + off(BWDOFF, 2, u, jl)) = h1;
    *(f16*)(p + off(BWDOFF, 3, u, jl)) = l1;
}

__device__ __forceinline__ void plswap(u32& a, u32& b) {
    u32x2 r = __builtin_amdgcn_permlane32_swap(a, b, false, false);
    a = r.x; b = r.y;
}

// r = v - f32(f16 half of h): single v_fma_mix_f32 (f16 source, f32 math)
__device__ __forceinline__ float fmix_lo(u32 h, float v, float fone) {
    float r;
    asm("v_fma_mix_f32 %0, -%1, %2, %3 op_sel_hi:[1,0,0]"
        : "=v"(r) : "v"(h), "v"(fone), "v"(v));
    return r;
}
__device__ __forceinline__ float fmix_hi(u32 h, float v, float fone) {
    float r;
    asm("v_fma_mix_f32 %0, -%1, %2, %3 op_sel:[1,0,0] op_sel_hi:[1,0,0]"
        : "=v"(r) : "v"(h), "v"(fone), "v"(v));
    return r;
}

// 4 direct global 16B loads (half chunk) into named reg set S (ping-pong).
#define LOADSET4(S, base) {                                               \
    const char* p_ = (base);                                              \
    S##0 = *(const f16x8*)(p_);                                           \
    S##1 = *(const f16x8*)(p_ + 1024);                                    \
    S##2 = *(const f16x8*)(p_ + 2048);                                    \
    S##3 = *(const f16x8*)(p_ + 3072); }

// vals[r] (own sample s32, row SROW(r)) -> B-frags (k-contig), hi + unscaled lo.
#define BUILD_FRAGS(F0, F1, L0, L1, V) {                                  \
    u32 owh[8], owl[8];                                                   \
    _Pragma("unroll")                                                     \
    for (int i_ = 0; i_ < 8; ++i_) {                                      \
        float v0_ = (V)[2*i_], v1_ = (V)[2*i_ + 1];                       \
        auto hp_ = __builtin_amdgcn_cvt_pkrtz(v0_, v1_);                  \
        owh[i_] = __builtin_bit_cast(u32, hp_);                           \
        float r0_ = fmix_lo(owh[i_], v0_, fone);                          \
        float r1_ = fmix_hi(owh[i_], v1_, fone);                          \
        auto lp_ = __builtin_amdgcn_cvt_pkrtz(r0_, r1_);                  \
        owl[i_] = __builtin_bit_cast(u32, lp_);                           \
    }                                                                     \
    {                                                                     \
        u32 a0_ = owh[0], b0_ = owh[2]; plswap(a0_, b0_);                 \
        u32 a1_ = owh[1], b1_ = owh[3]; plswap(a1_, b1_);                 \
        F0 = __builtin_bit_cast(f16x8, (u32x4){a0_, a1_, b0_, b1_});      \
        u32 c0_ = owh[4], d0_ = owh[6]; plswap(c0_, d0_);                 \
        u32 c1_ = owh[5], d1_ = owh[7]; plswap(c1_, d1_);                 \
        F1 = __builtin_bit_cast(f16x8, (u32x4){c0_, c1_, d0_, d1_});      \
        u32 e0_ = owl[0], f0_ = owl[2]; plswap(e0_, f0_);                 \
        u32 e1_ = owl[1], f1_ = owl[3]; plswap(e1_, f1_);                 \
        L0 = __builtin_bit_cast(f16x8, (u32x4){e0_, e1_, f0_, f1_});      \
        u32 g0_ = owl[4], h0_ = owl[6]; plswap(g0_, h0_);                 \
        u32 g1_ = owl[5], h1_ = owl[7]; plswap(g1_, h1_);                 \
        L1 = __builtin_bit_cast(f16x8, (u32x4){g0_, g1_, h0_, h1_});      \
    } }

#define MFMA(d, a, b, c) d = __builtin_amdgcn_mfma_f32_32x32x16_f16(a, b, c, 0, 0, 0)

__global__ __launch_bounds__(TPB, 2)
__attribute__((amdgpu_waves_per_eu(2, 2)))
void hopfield_mfma8(const float* __restrict__ x,
                    const float* __restrict__ b1,
                    const float* __restrict__ b2,
                    const f16* __restrict__ ws,
                    float* __restrict__ out) {
    __shared__ __align__(16) float sB1p[HID];   // 4 KB, SROW-permuted bias
    __shared__ __align__(16) float sB2p[UNITS];
    __shared__ u16 sMsk[WPB][NCH * 128];        // 32 KB relu masks (2 tiles/wave)

    const int tid = threadIdx.x;
    const int wv = tid >> 6, ln = tid & 63;
    const int s32 = ln & 31, gh = ln >> 5;

    for (int i = tid; i < HID; i += TPB) {
        int c = i >> 5, g_ = (i >> 4) & 1, r = i & 15;
        sB1p[i] = b1[c * 32 + ((r & 3) + ((r >> 2) << 3) + (g_ << 2))];
    }
    if (tid < UNITS) {
        int g_ = (tid >> 4) & 1, r = tid & 15;
        sB2p[tid] = b2[(r & 3) + ((r >> 2) << 3) + (g_ << 2)];
    }
    __syncthreads();          // the only block-wide barrier

    u16* mkb = &sMsk[wv][0];
    const float fone = 1.0f;

    // wave owns 64 samples: tile A = base..base+31, tile B = +32
    const long samp = (long)blockIdx.x * SPB + wv * 64 + s32;
    float zbA[16], zbB[16], accA[16], accB[16];
    {
        const float* xa = x + samp * UNITS;
        const float* xb = x + (samp + 32) * UNITS;
        #pragma unroll
        for (int q = 0; q < 4; ++q) {
            float4 va = *(const float4*)(xa + 8 * q + 4 * gh);
            float4 vb = *(const float4*)(xb + 8 * q + 4 * gh);
            zbA[4*q+0] = va.x; zbA[4*q+1] = va.y; zbA[4*q+2] = va.z; zbA[4*q+3] = va.w;
            zbB[4*q+0] = vb.x; zbB[4*q+1] = vb.y; zbB[4*q+2] = vb.z; zbB[4*q+3] = vb.w;
        }
    }

    f32x16 zeros;
    #pragma unroll
    for (int r = 0; r < 16; ++r) zeros[r] = 0.f;

    const char* pfwd = (const char*)ws + (size_t)ln * 16;
    const char* pbwd = pfwd + BWDOFF;

    f16x8 P0, P1, P2, P3;     // GEMM-1 weights of current chunk
    f16x8 Q0, Q1, Q2, Q3;     // GEMM-2 weights of current chunk
    LOADSET4(P, pfwd)         // prologue: fwd chunk 0 G1 in flight

    f16x8 zaA0h, zaA1h, zaA0l, zaA1l;
    f16x8 zaB0h, zaB1h, zaB0l, zaB1l;
    BUILD_FRAGS(zaA0h, zaA1h, zaA0l, zaA1l, zbA)
    BUILD_FRAGS(zaB0h, zaB1h, zaB0l, zaB1l, zbB)

    #pragma unroll 1
    for (int step = 0; step < 10; ++step) {
        #pragma unroll
        for (int r = 0; r < 16; ++r) { accA[r] = 0.f; accB[r] = 0.f; }

        #pragma unroll 1
        for (int sub = 0; sub < 4; ++sub) {
            f32x16 ymA, ymB;
            {   // Y^T accumulator init with b2 (SROW order)
                const float4* bp = (const float4*)(sB2p + gh * 16);
                float4 v0 = bp[0], v1 = bp[1], v2 = bp[2], v3 = bp[3];
                ymA[0]=v0.x; ymA[1]=v0.y; ymA[2]=v0.z; ymA[3]=v0.w;
                ymA[4]=v1.x; ymA[5]=v1.y; ymA[6]=v1.z; ymA[7]=v1.w;
                ymA[8]=v2.x; ymA[9]=v2.y; ymA[10]=v2.z; ymA[11]=v2.w;
                ymA[12]=v3.x; ymA[13]=v3.y; ymA[14]=v3.z; ymA[15]=v3.w;
                #pragma unroll
                for (int r = 0; r < 16; ++r) ymB[r] = ymA[r];
            }

            // ============ forward: dual-tile, 4 independent 3-chains =======
            #pragma unroll 1
            for (int c = 0; c < NCH; ++c) {
                LOADSET4(Q, pfwd + c * 8192 + 4096)     // G2 weights of c
                f32x16 hmA0, hmA1, hmB0, hmB1;          // k0/k1 split chains
                __builtin_amdgcn_s_setprio(1);
                MFMA(hmA0, P0, zaA0h, zeros); MFMA(hmB0, P0, zaB0h, zeros);
                MFMA(hmA1, P1, zaA1h, zeros); MFMA(hmB1, P1, zaB1h, zeros);
                MFMA(hmA0, P0, zaA0l, hmA0);  MFMA(hmB0, P0, zaB0l, hmB0);
                MFMA(hmA1, P1, zaA1l, hmA1);  MFMA(hmB1, P1, zaB1l, hmB1);
                MFMA(hmA0, P2, zaA0h, hmA0);  MFMA(hmB0, P2, zaB0h, hmB0);
                MFMA(hmA1, P3, zaA1h, hmA1);  MFMA(hmB1, P3, zaB1h, hmB1);
                __builtin_amdgcn_s_setprio(0);

                float bv[16];
                {
                    const float4* bp = (const float4*)(sB1p + c * 32 + gh * 16);
                    float4 b0 = bp[0], b1v = bp[1], b2v = bp[2], b3 = bp[3];
                    bv[0]=b0.x; bv[1]=b0.y; bv[2]=b0.z; bv[3]=b0.w;
                    bv[4]=b1v.x; bv[5]=b1v.y; bv[6]=b1v.z; bv[7]=b1v.w;
                    bv[8]=b2v.x; bv[9]=b2v.y; bv[10]=b2v.z; bv[11]=b2v.w;
                    bv[12]=b3.x; bv[13]=b3.y; bv[14]=b3.z; bv[15]=b3.w;
                }
                float rvA[16], rvB[16]; u32 mbA = 0, mbB = 0;
                #pragma unroll
                for (int r = 0; r < 16; ++r) {
                    float sA = (hmA0[r] + hmA1[r]) + bv[r];
                    float sB = (hmB0[r] + hmB1[r]) + bv[r];
                    if (sA > 0.f) mbA |= (1u << r);
                    if (sB > 0.f) mbB |= (1u << r);
                    rvA[r] = fmaxf(sA, 0.f);
                    rvB[r] = fmaxf(sB, 0.f);
                }
                mkb[c * 128 + ln] = (u16)mbA;
                mkb[c * 128 + 64 + ln] = (u16)mbB;

                f16x8 rfA0, rfA1, rlA0, rlA1, rfB0, rfB1, rlB0, rlB1;
                BUILD_FRAGS(rfA0, rfA1, rlA0, rlA1, rvA)
                BUILD_FRAGS(rfB0, rfB1, rlB0, rlB1, rvB)
                LOADSET4(P, (c < NCH - 1) ? (pfwd + (c + 1) * 8192) : pbwd)
                __builtin_amdgcn_s_setprio(1);
                MFMA(ymA, Q0, rfA0, ymA); MFMA(ymB, Q0, rfB0, ymB);
                MFMA(ymA, Q0, rlA0, ymA); MFMA(ymB, Q0, rlB0, ymB);
                MFMA(ymA, Q2, rfA0, ymA); MFMA(ymB, Q2, rfB0, ymB);
                MFMA(ymA, Q1, rfA1, ymA); MFMA(ymB, Q1, rfB1, ymB);
                MFMA(ymA, Q1, rlA1, ymA); MFMA(ymB, Q1, rlB1, ymB);
                MFMA(ymA, Q3, rfA1, ymA); MFMA(ymB, Q3, rfB1, ymB);
                __builtin_amdgcn_s_setprio(0);
            }

            // ============ G = 8*Y/||Y|| per tile — register-local ==========
            f16x8 gfA0, gfA1, glA0, glA1, gfB0, gfB1, glB0, glB1;
            {
                float yv[16], t = 0.f;
                #pragma unroll
                for (int r = 0; r < 16; ++r) {
                    float y = ymA[r]; yv[r] = y; t = fmaf(y, y, t);
                }
                t += __shfl_xor(t, 32, 64);
                float s8 = 8.0f * rsqrtf(t);
                #pragma unroll
                for (int r = 0; r < 16; ++r) yv[r] *= s8;
                BUILD_FRAGS(gfA0, gfA1, glA0, glA1, yv)
            }
            {
                float yv[16], t = 0.f;
                #pragma unroll
                for (int r = 0; r < 16; ++r) {
                    float y = ymB[r]; yv[r] = y; t = fmaf(y, y, t);
                }
                t += __shfl_xor(t, 32, 64);
                float s8 = 8.0f * rsqrtf(t);
                #pragma unroll
                for (int r = 0; r < 16; ++r) yv[r] *= s8;
                BUILD_FRAGS(gfB0, gfB1, glB0, glB1, yv)
            }

            f32x16 kmA, kmB;
            #pragma unroll
            for (int r = 0; r < 16; ++r) { kmA[r] = 0.f; kmB[r] = 0.f; }

            // ============ backward: dual-tile, 4 independent 3-chains ======
            #pragma unroll 1
            for (int c = 0; c < NCH; ++c) {
                LOADSET4(Q, pbwd + c * 8192 + 4096)     // G2 weights of c
                f32x16 gmA0, gmA1, gmB0, gmB1;
                __builtin_amdgcn_s_setprio(1);
                MFMA(gmA0, P0, gfA0, zeros); MFMA(gmB0, P0, gfB0, zeros);
                MFMA(gmA1, P1, gfA1, zeros); MFMA(gmB1, P1, gfB1, zeros);
                MFMA(gmA0, P0, glA0, gmA0);  MFMA(gmB0, P0, glB0, gmB0);
                MFMA(gmA1, P1, glA1, gmA1);  MFMA(gmB1, P1, glB1, gmB1);
                MFMA(gmA0, P2, gfA0, gmA0);  MFMA(gmB0, P2, gfB0, gmB0);
                MFMA(gmA1, P3, gfA1, gmA1);  MFMA(gmB1, P3, gfB1, gmB1);
                __builtin_amdgcn_s_setprio(0);

                u32 mbA = mkb[c * 128 + ln];
                u32 mbB = mkb[c * 128 + 64 + ln];
                float mvA[16], mvB[16];
                #pragma unroll
                for (int r = 0; r < 16; ++r) {
                    float gA = gmA0[r] + gmA1[r];
                    float gB = gmB0[r] + gmB1[r];
                    mvA[r] = (mbA & (1u << r)) ? -gA : 0.f;
                    mvB[r] = (mbB & (1u << r)) ? -gB : 0.f;
                }

                f16x8 mfA0, mfA1, mlA0, mlA1, mfB0, mfB1, mlB0, mlB1;
                BUILD_FRAGS(mfA0, mfA1, mlA0, mlA1, mvA)
                BUILD_FRAGS(mfB0, mfB1, mlB0, mlB1, mvB)
                LOADSET4(P, (c < NCH - 1) ? (pbwd + (c + 1) * 8192) : pfwd)
                __builtin_amdgcn_s_setprio(1);
                MFMA(kmA, Q0, mfA0, kmA); MFMA(kmB, Q0, mfB0, kmB);
                MFMA(kmA, Q0, mlA0, kmA); MFMA(kmB, Q0, mlB0, kmB);
                MFMA(kmA, Q2, mfA0, kmA); MFMA(kmB, Q2, mfB0, kmB);
                MFMA(kmA, Q1, mfA1, kmA); MFMA(kmB, Q1, mfB1, kmB);
                MFMA(kmA, Q1, mlA1, kmA); MFMA(kmB, Q1, mlB1, kmB);
                MFMA(kmA, Q3, mfA1, kmA); MFMA(kmB, Q3, mfB1, kmB);
                __builtin_amdgcn_s_setprio(0);
            }

            // ============ RK4 bookkeeping + fused za rebuild ==============
            if (sub < 3) {
                float aw = (sub == 0) ? 1.f : 2.f;
                float cw = (sub == 2) ? 0.1f : 0.05f;
                float vzA[16], vzB[16];
                #pragma unroll
                for (int r = 0; r < 16; ++r) {
                    float ka = kmA[r], kb = kmB[r];
                    accA[r] += aw * ka;           accB[r] += aw * kb;
                    vzA[r] = fmaf(cw, ka, zbA[r]); vzB[r] = fmaf(cw, kb, zbB[r]);
                }
                BUILD_FRAGS(zaA0h, zaA1h, zaA0l, zaA1l, vzA)
                BUILD_FRAGS(zaB0h, zaB1h, zaB0l, zaB1l, vzB)
            } else {
                #pragma unroll
                for (int r = 0; r < 16; ++r) { accA[r] += kmA[r]; accB[r] += kmB[r]; }
            }
        } // sub

        #pragma unroll
        for (int r = 0; r < 16; ++r) {
            zbA[r] = fmaf(0.1f / 6.0f, accA[r], zbA[r]);
            zbB[r] = fmaf(0.1f / 6.0f, accB[r], zbB[r]);
        }
        BUILD_FRAGS(zaA0h, zaA1h, zaA0l, zaA1l, zbA)
        BUILD_FRAGS(zaB0h, zaB1h, zaB0l, zaB1l, zbB)
    } // step

    {
        float* oa = out + samp * UNITS;
        float* ob = out + (samp + 32) * UNITS;
        #pragma unroll
        for (int q = 0; q < 4; ++q) {
            float4 va, vb;
            va.x = zbA[4*q+0]; va.y = zbA[4*q+1]; va.z = zbA[4*q+2]; va.w = zbA[4*q+3];
            vb.x = zbB[4*q+0]; vb.y = zbB[4*q+1]; vb.z = zbB[4*q+2]; vb.w = zbB[4*q+3];
            *(float4*)(oa + 8 * q + 4 * gh) = va;
            *(float4*)(ob + 8 * q + 4 * gh) = vb;
        }
    }
}

extern "C" void kernel_launch(void* const* d_in, const int* in_sizes, int n_in,
                              void* d_out, int out_size, void* d_ws, size_t ws_size,
                              hipStream_t stream) {
    const float* x  = (const float*)d_in[0];
    const float* W1 = (const float*)d_in[1];
    const float* b1 = (const float*)d_in[2];
    const float* W2 = (const float*)d_in[3];
    const float* b2 = (const float*)d_in[4];
    float* out = (float*)d_out;
    f16* ws = (f16*)d_ws;   // 512 KB
    hipLaunchKernelGGL(prep_weights, dim3(128), dim3(256), 0, stream, W1, W2, ws);
    hipLaunchKernelGGL(hopfield_mfma8, dim3(NBLK), dim3(TPB), 0, stream,
                       x, b1, b2, ws, out);
}

// Round 18
// 3930.960 us; speedup vs baseline: 1.0730x; 1.0730x over previous
//
#include <hip/hip_runtime.h>

typedef _Float16 f16;
typedef __attribute__((ext_vector_type(8))) _Float16 f16x8;
typedef __attribute__((ext_vector_type(16))) float f32x16;
typedef __attribute__((ext_vector_type(2))) unsigned int u32x2;
typedef __attribute__((ext_vector_type(4))) unsigned int u32x4;
typedef unsigned int u32;
typedef unsigned short u16;

#define UNITS 32
#define HID   1024
#define NCH   32      // 32 chunks of 32 j
#define TPB   256     // 4 waves
#define WPB   4
#define SPB   256     // samples per block: 4 waves x 64 (2 tiles of 32)
#define NBLK  512
#define BWDOFF 262144

static_assert(NBLK * SPB == 131072, "grid covers batch");

// d_ws (512 KB): two regions (FWD @0, BWD @256KB), each
// [c:32][load:8][lane:64][16B], load = slice*2 + ks.
// FWD slices: 0/1 = W1^T hi/lo (A of H^T=W1^T@Z^T), 2/3 = W2^T hi/lo (A of Y^T)
// BWD slices: 0/1 = W2  hi/lo (A of GR^T=W2@G^T),   2/3 = W1  hi/lo (A of K^T)
// lo residuals UNSCALED: lo = f16(v - hi); all 3 split MFMAs share one C.
__global__ void prep_weights(const float* __restrict__ W1,
                             const float* __restrict__ W2,
                             f16* __restrict__ ws) {
    int idx = blockIdx.x * 256 + threadIdx.x;   // (c, jl, u)
    int c = idx >> 10, rem = idx & 1023;
    int jl = rem >> 5, u = rem & 31;
    int j = c * 32 + jl;
    float w1 = W1[u * HID + j];
    f16 h1 = (f16)w1;
    f16 l1 = (f16)(w1 - (float)h1);
    float w2 = W2[j * UNITS + u];
    f16 h2 = (f16)w2;
    f16 l2 = (f16)(w2 - (float)h2);
    char* p = (char*)ws;
    auto off = [&](int region, int slice, int row, int k) {
        int ks = k >> 4;
        int lane = row + ((k >> 3) & 1) * 32;
        return region + c * 8192 + (slice * 2 + ks) * 1024 + lane * 16 + (k & 7) * 2;
    };
    *(f16*)(p + off(0, 0, jl, u))      = h1;
    *(f16*)(p + off(0, 1, jl, u))      = l1;
    *(f16*)(p + off(0, 2, u, jl))      = h2;
    *(f16*)(p + off(0, 3, u, jl))      = l2;
    *(f16*)(p + off(BWDOFF, 0, jl, u)) = h2;
    *(f16*)(p + off(BWDOFF, 1, jl, u)) = l2;
    *(f16*)(p + off(BWDOFF, 2, u, jl)) = h1;
    *(f16*)(p + off(BWDOFF, 3, u, jl)) = l1;
}

__device__ __forceinline__ void plswap(u32& a, u32& b) {
    u32x2 r = __builtin_amdgcn_permlane32_swap(a, b, false, false);
    a = r.x; b = r.y;
}

// 4 direct global 16B loads (half chunk) into named reg set S (ping-pong).
#define LOADSET4(S, base) {                                               \
    const char* p_ = (base);                                              \
    S##0 = *(const f16x8*)(p_);                                           \
    S##1 = *(const f16x8*)(p_ + 1024);                                    \
    S##2 = *(const f16x8*)(p_ + 2048);                                    \
    S##3 = *(const f16x8*)(p_ + 3072); }

// vals[r] (own sample s32, row SROW(r)) -> B-frags (k-contig), hi + unscaled lo.
// lo residual fused: v_fma_mixlo/hi_f16 computes f16(v - hi) in one op each.
#define BUILD_FRAGS(F0, F1, L0, L1, V) {                                  \
    u32 owh[8], owl[8];                                                   \
    _Pragma("unroll")                                                     \
    for (int i_ = 0; i_ < 8; ++i_) {                                      \
        float v0_ = (V)[2*i_], v1_ = (V)[2*i_ + 1];                       \
        auto hp_ = __builtin_amdgcn_cvt_pkrtz(v0_, v1_);                  \
        owh[i_] = __builtin_bit_cast(u32, hp_);                           \
        u32 lw_;                                                          \
        asm("v_fma_mixlo_f16 %0, -%1, %2, %3 op_sel_hi:[1,0,0]\n\t"       \
            "v_fma_mixhi_f16 %0, -%1, %2, %4 op_sel:[1,0,0] op_sel_hi:[1,0,0]" \
            : "=&v"(lw_)                                                  \
            : "v"(owh[i_]), "v"(fone), "v"(v0_), "v"(v1_));               \
        owl[i_] = lw_;                                                    \
    }                                                                     \
    {                                                                     \
        u32 a0_ = owh[0], b0_ = owh[2]; plswap(a0_, b0_);                 \
        u32 a1_ = owh[1], b1_ = owh[3]; plswap(a1_, b1_);                 \
        F0 = __builtin_bit_cast(f16x8, (u32x4){a0_, a1_, b0_, b1_});      \
        u32 c0_ = owh[4], d0_ = owh[6]; plswap(c0_, d0_);                 \
        u32 c1_ = owh[5], d1_ = owh[7]; plswap(c1_, d1_);                 \
        F1 = __builtin_bit_cast(f16x8, (u32x4){c0_, c1_, d0_, d1_});      \
        u32 e0_ = owl[0], f0_ = owl[2]; plswap(e0_, f0_);                 \
        u32 e1_ = owl[1], f1_ = owl[3]; plswap(e1_, f1_);                 \
        L0 = __builtin_bit_cast(f16x8, (u32x4){e0_, e1_, f0_, f1_});      \
        u32 g0_ = owl[4], h0_ = owl[6]; plswap(g0_, h0_);                 \
        u32 g1_ = owl[5], h1_ = owl[7]; plswap(g1_, h1_);                 \
        L1 = __builtin_bit_cast(f16x8, (u32x4){g0_, g1_, h0_, h1_});      \
    } }

#define MFMA(d, a, b, c) d = __builtin_amdgcn_mfma_f32_32x32x16_f16(a, b, c, 0, 0, 0)

// load 16 f32 (SROW-permuted vector) from LDS into an f32x16
#define LD16(DST, PTR) {                                                  \
    const float4* bp_ = (const float4*)(PTR);                             \
    float4 t0_ = bp_[0], t1_ = bp_[1], t2_ = bp_[2], t3_ = bp_[3];        \
    DST[0]=t0_.x; DST[1]=t0_.y; DST[2]=t0_.z; DST[3]=t0_.w;               \
    DST[4]=t1_.x; DST[5]=t1_.y; DST[6]=t1_.z; DST[7]=t1_.w;               \
    DST[8]=t2_.x; DST[9]=t2_.y; DST[10]=t2_.z; DST[11]=t2_.w;             \
    DST[12]=t3_.x; DST[13]=t3_.y; DST[14]=t3_.z; DST[15]=t3_.w; }

__global__ __launch_bounds__(TPB, 2)
__attribute__((amdgpu_waves_per_eu(2, 2)))
void hopfield_mfma9(const float* __restrict__ x,
                    const float* __restrict__ b1,
                    const float* __restrict__ b2,
                    const f16* __restrict__ ws,
                    float* __restrict__ out) {
    __shared__ __align__(16) float sB1p[HID];   // 4 KB, SROW-permuted bias
    __shared__ __align__(16) float sB2p[UNITS];
    __shared__ u16 sMsk[WPB][NCH * 128];        // 32 KB relu masks (2 tiles/wave)

    const int tid = threadIdx.x;
    const int wv = tid >> 6, ln = tid & 63;
    const int s32 = ln & 31, gh = ln >> 5;

    for (int i = tid; i < HID; i += TPB) {
        int c = i >> 5, g_ = (i >> 4) & 1, r = i & 15;
        sB1p[i] = b1[c * 32 + ((r & 3) + ((r >> 2) << 3) + (g_ << 2))];
    }
    if (tid < UNITS) {
        int g_ = (tid >> 4) & 1, r = tid & 15;
        sB2p[tid] = b2[(r & 3) + ((r >> 2) << 3) + (g_ << 2)];
    }
    __syncthreads();          // the only block-wide barrier

    u16* mkb = &sMsk[wv][0];
    const float fone = 1.0f;

    // wave owns 64 samples: tile A = base..base+31, tile B = +32
    const long samp = (long)blockIdx.x * SPB + wv * 64 + s32;
    float zbA[16], zbB[16], accA[16], accB[16];
    {
        const float* xa = x + samp * UNITS;
        const float* xb = x + (samp + 32) * UNITS;
        #pragma unroll
        for (int q = 0; q < 4; ++q) {
            float4 va = *(const float4*)(xa + 8 * q + 4 * gh);
            float4 vb = *(const float4*)(xb + 8 * q + 4 * gh);
            zbA[4*q+0] = va.x; zbA[4*q+1] = va.y; zbA[4*q+2] = va.z; zbA[4*q+3] = va.w;
            zbB[4*q+0] = vb.x; zbB[4*q+1] = vb.y; zbB[4*q+2] = vb.z; zbB[4*q+3] = vb.w;
        }
    }

    f32x16 zeros;
    #pragma unroll
    for (int r = 0; r < 16; ++r) zeros[r] = 0.f;

    const char* pfwd = (const char*)ws + (size_t)ln * 16;
    const char* pbwd = pfwd + BWDOFF;

    f16x8 P0, P1, P2, P3;     // GEMM-1 weights of current chunk
    f16x8 Q0, Q1, Q2, Q3;     // GEMM-2 weights of current chunk
    LOADSET4(P, pfwd)         // prologue: fwd chunk 0 G1 in flight

    f16x8 zaA0h, zaA1h, zaA0l, zaA1l;
    f16x8 zaB0h, zaB1h, zaB0l, zaB1l;
    BUILD_FRAGS(zaA0h, zaA1h, zaA0l, zaA1l, zbA)
    BUILD_FRAGS(zaB0h, zaB1h, zaB0l, zaB1l, zbB)

    #pragma unroll 1
    for (int step = 0; step < 10; ++step) {
        #pragma unroll
        for (int r = 0; r < 16; ++r) { accA[r] = 0.f; accB[r] = 0.f; }

        #pragma unroll 1
        for (int sub = 0; sub < 4; ++sub) {
            f32x16 ymA, ymB;
            LD16(ymA, sB2p + gh * 16)     // Y^T accumulator init with b2
            #pragma unroll
            for (int r = 0; r < 16; ++r) ymB[r] = ymA[r];

            // ============ forward: bias-as-C, single chain per tile ========
            #pragma unroll 1
            for (int c = 0; c < NCH; ++c) {
                LOADSET4(Q, pfwd + c * 8192 + 4096)     // G2 weights of c
                f32x16 cb;
                LD16(cb, sB1p + c * 32 + gh * 16)       // b1 slice as C-init
                f32x16 hmA, hmB;
                MFMA(hmA, P0, zaA0h, cb);  MFMA(hmB, P0, zaB0h, cb);
                MFMA(hmA, P0, zaA0l, hmA); MFMA(hmB, P0, zaB0l, hmB);
                MFMA(hmA, P2, zaA0h, hmA); MFMA(hmB, P2, zaB0h, hmB);
                MFMA(hmA, P1, zaA1h, hmA); MFMA(hmB, P1, zaB1h, hmB);
                MFMA(hmA, P1, zaA1l, hmA); MFMA(hmB, P1, zaB1l, hmB);
                MFMA(hmA, P3, zaA1h, hmA); MFMA(hmB, P3, zaB1h, hmB);

                float rvA[16], rvB[16]; u32 mbA = 0, mbB = 0;
                #pragma unroll
                for (int r = 0; r < 16; ++r) {
                    float sA = hmA[r], sB = hmB[r];
                    if (sA > 0.f) mbA |= (1u << r);
                    if (sB > 0.f) mbB |= (1u << r);
                    rvA[r] = fmaxf(sA, 0.f);
                    rvB[r] = fmaxf(sB, 0.f);
                }
                mkb[c * 128 + ln] = (u16)mbA;
                mkb[c * 128 + 64 + ln] = (u16)mbB;

                f16x8 rfA0, rfA1, rlA0, rlA1, rfB0, rfB1, rlB0, rlB1;
                BUILD_FRAGS(rfA0, rfA1, rlA0, rlA1, rvA)
                BUILD_FRAGS(rfB0, rfB1, rlB0, rlB1, rvB)
                LOADSET4(P, (c < NCH - 1) ? (pfwd + (c + 1) * 8192) : pbwd)
                MFMA(ymA, Q0, rfA0, ymA); MFMA(ymB, Q0, rfB0, ymB);
                MFMA(ymA, Q0, rlA0, ymA); MFMA(ymB, Q0, rlB0, ymB);
                MFMA(ymA, Q2, rfA0, ymA); MFMA(ymB, Q2, rfB0, ymB);
                MFMA(ymA, Q1, rfA1, ymA); MFMA(ymB, Q1, rfB1, ymB);
                MFMA(ymA, Q1, rlA1, ymA); MFMA(ymB, Q1, rlB1, ymB);
                MFMA(ymA, Q3, rfA1, ymA); MFMA(ymB, Q3, rfB1, ymB);
            }

            // ============ G = 8*Y/||Y|| per tile — register-local ==========
            f16x8 gfA0, gfA1, glA0, glA1, gfB0, gfB1, glB0, glB1;
            {
                float yv[16], t = 0.f;
                #pragma unroll
                for (int r = 0; r < 16; ++r) {
                    float y = ymA[r]; yv[r] = y; t = fmaf(y, y, t);
                }
                t += __shfl_xor(t, 32, 64);
                float s8 = 8.0f * rsqrtf(t);
                #pragma unroll
                for (int r = 0; r < 16; ++r) yv[r] *= s8;
                BUILD_FRAGS(gfA0, gfA1, glA0, glA1, yv)
            }
            {
                float yv[16], t = 0.f;
                #pragma unroll
                for (int r = 0; r < 16; ++r) {
                    float y = ymB[r]; yv[r] = y; t = fmaf(y, y, t);
                }
                t += __shfl_xor(t, 32, 64);
                float s8 = 8.0f * rsqrtf(t);
                #pragma unroll
                for (int r = 0; r < 16; ++r) yv[r] *= s8;
                BUILD_FRAGS(gfB0, gfB1, glB0, glB1, yv)
            }

            f32x16 kmA, kmB;
            #pragma unroll
            for (int r = 0; r < 16; ++r) { kmA[r] = 0.f; kmB[r] = 0.f; }

            // ============ backward: dual-tile ==============================
            #pragma unroll 1
            for (int c = 0; c < NCH; ++c) {
                LOADSET4(Q, pbwd + c * 8192 + 4096)     // G2 weights of c
                f32x16 gmA, gmB;
                MFMA(gmA, P0, gfA0, zeros); MFMA(gmB, P0, gfB0, zeros);
                MFMA(gmA, P0, glA0, gmA);   MFMA(gmB, P0, glB0, gmB);
                MFMA(gmA, P2, gfA0, gmA);   MFMA(gmB, P2, gfB0, gmB);
                MFMA(gmA, P1, gfA1, gmA);   MFMA(gmB, P1, gfB1, gmB);
                MFMA(gmA, P1, glA1, gmA);   MFMA(gmB, P1, glB1, gmB);
                MFMA(gmA, P3, gfA1, gmA);   MFMA(gmB, P3, gfB1, gmB);

                u32 mbA = mkb[c * 128 + ln];
                u32 mbB = mkb[c * 128 + 64 + ln];
                float mvA[16], mvB[16];
                #pragma unroll
                for (int r = 0; r < 16; ++r) {
                    mvA[r] = (mbA & (1u << r)) ? -gmA[r] : 0.f;
                    mvB[r] = (mbB & (1u << r)) ? -gmB[r] : 0.f;
                }

                f16x8 mfA0, mfA1, mlA0, mlA1, mfB0, mfB1, mlB0, mlB1;
                BUILD_FRAGS(mfA0, mfA1, mlA0, mlA1, mvA)
                BUILD_FRAGS(mfB0, mfB1, mlB0, mlB1, mvB)
                LOADSET4(P, (c < NCH - 1) ? (pbwd + (c + 1) * 8192) : pfwd)
                MFMA(kmA, Q0, mfA0, kmA); MFMA(kmB, Q0, mfB0, kmB);
                MFMA(kmA, Q0, mlA0, kmA); MFMA(kmB, Q0, mlB0, kmB);
                MFMA(kmA, Q2, mfA0, kmA); MFMA(kmB, Q2, mfB0, kmB);
                MFMA(kmA, Q1, mfA1, kmA); MFMA(kmB, Q1, mfB1, kmB);
                MFMA(kmA, Q1, mlA1, kmA); MFMA(kmB, Q1, mlB1, kmB);
                MFMA(kmA, Q3, mfA1, kmA); MFMA(kmB, Q3, mfB1, kmB);
            }

            // ============ RK4 bookkeeping + fused za rebuild ==============
            if (sub < 3) {
                float aw = (sub == 0) ? 1.f : 2.f;
                float cw = (sub == 2) ? 0.1f : 0.05f;
                float vzA[16], vzB[16];
                #pragma unroll
                for (int r = 0; r < 16; ++r) {
                    float ka = kmA[r], kb = kmB[r];
                    accA[r] += aw * ka;           accB[r] += aw * kb;
                    vzA[r] = fmaf(cw, ka, zbA[r]); vzB[r] = fmaf(cw, kb, zbB[r]);
                }
                BUILD_FRAGS(zaA0h, zaA1h, zaA0l, zaA1l, vzA)
                BUILD_FRAGS(zaB0h, zaB1h, zaB0l, zaB1l, vzB)
            } else {
                #pragma unroll
                for (int r = 0; r < 16; ++r) { accA[r] += kmA[r]; accB[r] += kmB[r]; }
            }
        } // sub

        #pragma unroll
        for (int r = 0; r < 16; ++r) {
            zbA[r] = fmaf(0.1f / 6.0f, accA[r], zbA[r]);
            zbB[r] = fmaf(0.1f / 6.0f, accB[r], zbB[r]);
        }
        BUILD_FRAGS(zaA0h, zaA1h, zaA0l, zaA1l, zbA)
        BUILD_FRAGS(zaB0h, zaB1h, zaB0l, zaB1l, zbB)
    } // step

    {
        float* oa = out + samp * UNITS;
        float* ob = out + (samp + 32) * UNITS;
        #pragma unroll
        for (int q = 0; q < 4; ++q) {
            float4 va, vb;
            va.x = zbA[4*q+0]; va.y = zbA[4*q+1]; va.z = zbA[4*q+2]; va.w = zbA[4*q+3];
            vb.x = zbB[4*q+0]; vb.y = zbB[4*q+1]; vb.z = zbB[4*q+2]; vb.w = zbB[4*q+3];
            *(float4*)(oa + 8 * q + 4 * gh) = va;
            *(float4*)(ob + 8 * q + 4 * gh) = vb;
        }
    }
}

extern "C" void kernel_launch(void* const* d_in, const int* in_sizes, int n_in,
                              void* d_out, int out_size, void* d_ws, size_t ws_size,
                              hipStream_t stream) {
    const float* x  = (const float*)d_in[0];
    const float* W1 = (const float*)d_in[1];
    const float* b1 = (const float*)d_in[2];
    const float* W2 = (const float*)d_in[3];
    const float* b2 = (const float*)d_in[4];
    float* out = (float*)d_out;
    f16* ws = (f16*)d_ws;   // 512 KB
    hipLaunchKernelGGL(prep_weights, dim3(128), dim3(256), 0, stream, W1, W2, ws);
    hipLaunchKernelGGL(hopfield_mfma9, dim3(NBLK), dim3(TPB), 0, stream,
                       x, b1, b2, ws, out);
}

// Round 19
// 3882.666 us; speedup vs baseline: 1.0864x; 1.0124x over previous
//
#include <hip/hip_runtime.h>

typedef _Float16 f16;
typedef __attribute__((ext_vector_type(8))) _Float16 f16x8;
typedef __attribute__((ext_vector_type(16))) float f32x16;
typedef __attribute__((ext_vector_type(2))) unsigned int u32x2;
typedef __attribute__((ext_vector_type(4))) unsigned int u32x4;
typedef unsigned int u32;
typedef unsigned short u16;

#define UNITS 32
#define HID   1024
#define NCH   32      // 32 chunks of 32 j
#define TPB   256     // 4 waves
#define WPB   4
#define SPB   256     // samples per block: 4 waves x 64 (2 tiles of 32)
#define NBLK  512
#define BWDOFF 262144

static_assert(NBLK * SPB == 131072, "grid covers batch");

// d_ws (512 KB): two regions (FWD @0, BWD @256KB), each
// [c:32][load:8][lane:64][16B], load = slice*2 + ks.
// FWD slices: 0/1 = W1^T hi/lo (A of H^T=W1^T@Z^T), 2/3 = W2^T hi/lo (A of Y^T)
// BWD slices: 0/1 = W2  hi/lo (A of GR^T=W2@G^T),   2/3 = W1  hi/lo (A of K^T)
// lo residuals UNSCALED: lo = f16(v - hi); all 3 split MFMAs share one C.
__global__ void prep_weights(const float* __restrict__ W1,
                             const float* __restrict__ W2,
                             f16* __restrict__ ws) {
    int idx = blockIdx.x * 256 + threadIdx.x;   // (c, jl, u)
    int c = idx >> 10, rem = idx & 1023;
    int jl = rem >> 5, u = rem & 31;
    int j = c * 32 + jl;
    float w1 = W1[u * HID + j];
    f16 h1 = (f16)w1;
    f16 l1 = (f16)(w1 - (float)h1);
    float w2 = W2[j * UNITS + u];
    f16 h2 = (f16)w2;
    f16 l2 = (f16)(w2 - (float)h2);
    char* p = (char*)ws;
    auto off = [&](int region, int slice, int row, int k) {
        int ks = k >> 4;
        int lane = row + ((k >> 3) & 1) * 32;
        return region + c * 8192 + (slice * 2 + ks) * 1024 + lane * 16 + (k & 7) * 2;
    };
    *(f16*)(p + off(0, 0, jl, u))      = h1;
    *(f16*)(p + off(0, 1, jl, u))      = l1;
    *(f16*)(p + off(0, 2, u, jl))      = h2;
    *(f16*)(p + off(0, 3, u, jl))      = l2;
    *(f16*)(p + off(BWDOFF, 0, jl, u)) = h2;
    *(f16*)(p + off(BWDOFF, 1, jl, u)) = l2;
    *(f16*)(p + off(BWDOFF, 2, u, jl)) = h1;
    *(f16*)(p + off(BWDOFF, 3, u, jl)) = l1;
}

__device__ __forceinline__ void plswap(u32& a, u32& b) {
    u32x2 r = __builtin_amdgcn_permlane32_swap(a, b, false, false);
    a = r.x; b = r.y;
}

// 4 direct global 16B loads (half chunk) into named reg set S (ping-pong).
#define LOADSET4(S, base) {                                               \
    const char* p_ = (base);                                              \
    S##0 = *(const f16x8*)(p_);                                           \
    S##1 = *(const f16x8*)(p_ + 1024);                                    \
    S##2 = *(const f16x8*)(p_ + 2048);                                    \
    S##3 = *(const f16x8*)(p_ + 3072); }

// vals[r] (own sample s32, row SROW(r)) -> B-frags (k-contig), hi + unscaled lo.
// lo residual fused: v_fma_mixlo/hi_f16 computes f16(v - hi) in one op each.
#define BUILD_FRAGS(F0, F1, L0, L1, V) {                                  \
    u32 owh[8], owl[8];                                                   \
    _Pragma("unroll")                                                     \
    for (int i_ = 0; i_ < 8; ++i_) {                                      \
        float v0_ = (V)[2*i_], v1_ = (V)[2*i_ + 1];                       \
        auto hp_ = __builtin_amdgcn_cvt_pkrtz(v0_, v1_);                  \
        owh[i_] = __builtin_bit_cast(u32, hp_);                           \
        u32 lw_;                                                          \
        asm("v_fma_mixlo_f16 %0, -%1, %2, %3 op_sel_hi:[1,0,0]\n\t"       \
            "v_fma_mixhi_f16 %0, -%1, %2, %4 op_sel:[1,0,0] op_sel_hi:[1,0,0]" \
            : "=&v"(lw_)                                                  \
            : "v"(owh[i_]), "v"(fone), "v"(v0_), "v"(v1_));               \
        owl[i_] = lw_;                                                    \
    }                                                                     \
    {                                                                     \
        u32 a0_ = owh[0], b0_ = owh[2]; plswap(a0_, b0_);                 \
        u32 a1_ = owh[1], b1_ = owh[3]; plswap(a1_, b1_);                 \
        F0 = __builtin_bit_cast(f16x8, (u32x4){a0_, a1_, b0_, b1_});      \
        u32 c0_ = owh[4], d0_ = owh[6]; plswap(c0_, d0_);                 \
        u32 c1_ = owh[5], d1_ = owh[7]; plswap(c1_, d1_);                 \
        F1 = __builtin_bit_cast(f16x8, (u32x4){c0_, c1_, d0_, d1_});      \
        u32 e0_ = owl[0], f0_ = owl[2]; plswap(e0_, f0_);                 \
        u32 e1_ = owl[1], f1_ = owl[3]; plswap(e1_, f1_);                 \
        L0 = __builtin_bit_cast(f16x8, (u32x4){e0_, e1_, f0_, f1_});      \
        u32 g0_ = owl[4], h0_ = owl[6]; plswap(g0_, h0_);                 \
        u32 g1_ = owl[5], h1_ = owl[7]; plswap(g1_, h1_);                 \
        L1 = __builtin_bit_cast(f16x8, (u32x4){g0_, g1_, h0_, h1_});      \
    } }

#define MFMA(d, a, b, c) d = __builtin_amdgcn_mfma_f32_32x32x16_f16(a, b, c, 0, 0, 0)

__global__ __launch_bounds__(TPB, 2)
__attribute__((amdgpu_waves_per_eu(2, 2)))
void hopfield_mfma10(const float* __restrict__ x,
                     const float* __restrict__ b1,
                     const float* __restrict__ b2,
                     const f16* __restrict__ ws,
                     float* __restrict__ out) {
    __shared__ __align__(16) float sB1p[HID];   // 4 KB, SROW-permuted bias
    __shared__ __align__(16) float sB2p[UNITS];
    __shared__ u16 sMsk[WPB][NCH * 128];        // 32 KB relu masks (2 tiles/wave)

    const int tid = threadIdx.x;
    const int wv = tid >> 6, ln = tid & 63;
    const int s32 = ln & 31, gh = ln >> 5;

    for (int i = tid; i < HID; i += TPB) {
        int c = i >> 5, g_ = (i >> 4) & 1, r = i & 15;
        sB1p[i] = b1[c * 32 + ((r & 3) + ((r >> 2) << 3) + (g_ << 2))];
    }
    if (tid < UNITS) {
        int g_ = (tid >> 4) & 1, r = tid & 15;
        sB2p[tid] = b2[(r & 3) + ((r >> 2) << 3) + (g_ << 2)];
    }
    __syncthreads();          // the only block-wide barrier

    u16* mkb = &sMsk[wv][0];
    const float fone = 1.0f;

    // wave owns 64 samples: tile A = base..base+31, tile B = +32
    const long samp = (long)blockIdx.x * SPB + wv * 64 + s32;
    float zbA[16], zbB[16], accA[16], accB[16];
    {
        const float* xa = x + samp * UNITS;
        const float* xb = x + (samp + 32) * UNITS;
        #pragma unroll
        for (int q = 0; q < 4; ++q) {
            float4 va = *(const float4*)(xa + 8 * q + 4 * gh);
            float4 vb = *(const float4*)(xb + 8 * q + 4 * gh);
            zbA[4*q+0] = va.x; zbA[4*q+1] = va.y; zbA[4*q+2] = va.z; zbA[4*q+3] = va.w;
            zbB[4*q+0] = vb.x; zbB[4*q+1] = vb.y; zbB[4*q+2] = vb.z; zbB[4*q+3] = vb.w;
        }
    }

    f32x16 zeros;
    #pragma unroll
    for (int r = 0; r < 16; ++r) zeros[r] = 0.f;

    const char* pfwd = (const char*)ws + (size_t)ln * 16;
    const char* pbwd = pfwd + BWDOFF;

    f16x8 P0, P1, P2, P3;     // GEMM-1 weights of current chunk
    f16x8 Q0, Q1, Q2, Q3;     // GEMM-2 weights of current chunk
    LOADSET4(P, pfwd)         // prologue: fwd chunk 0 G1 in flight

    f16x8 zaA0h, zaA1h, zaA0l, zaA1l;
    f16x8 zaB0h, zaB1h, zaB0l, zaB1l;
    BUILD_FRAGS(zaA0h, zaA1h, zaA0l, zaA1l, zbA)
    BUILD_FRAGS(zaB0h, zaB1h, zaB0l, zaB1l, zbB)

    #pragma unroll 1
    for (int step = 0; step < 10; ++step) {
        #pragma unroll
        for (int r = 0; r < 16; ++r) { accA[r] = 0.f; accB[r] = 0.f; }

        #pragma unroll 1
        for (int sub = 0; sub < 4; ++sub) {
            f32x16 ymA, ymB;
            {   // Y^T accumulator init with b2 (SROW order)
                const float4* bp = (const float4*)(sB2p + gh * 16);
                float4 v0 = bp[0], v1 = bp[1], v2 = bp[2], v3 = bp[3];
                ymA[0]=v0.x; ymA[1]=v0.y; ymA[2]=v0.z; ymA[3]=v0.w;
                ymA[4]=v1.x; ymA[5]=v1.y; ymA[6]=v1.z; ymA[7]=v1.w;
                ymA[8]=v2.x; ymA[9]=v2.y; ymA[10]=v2.z; ymA[11]=v2.w;
                ymA[12]=v3.x; ymA[13]=v3.y; ymA[14]=v3.z; ymA[15]=v3.w;
                #pragma unroll
                for (int r = 0; r < 16; ++r) ymB[r] = ymA[r];
            }

            // ============ forward: dual-tile, interleaved MFMA chains ======
            #pragma unroll 1
            for (int c = 0; c < NCH; ++c) {
                LOADSET4(Q, pfwd + c * 8192 + 4096)     // G2 weights of c
                f32x16 hmA, hmB;
                MFMA(hmA, P0, zaA0h, zeros); MFMA(hmB, P0, zaB0h, zeros);
                MFMA(hmA, P0, zaA0l, hmA);   MFMA(hmB, P0, zaB0l, hmB);
                MFMA(hmA, P2, zaA0h, hmA);   MFMA(hmB, P2, zaB0h, hmB);
                MFMA(hmA, P1, zaA1h, hmA);   MFMA(hmB, P1, zaB1h, hmB);
                MFMA(hmA, P1, zaA1l, hmA);   MFMA(hmB, P1, zaB1l, hmB);
                MFMA(hmA, P3, zaA1h, hmA);   MFMA(hmB, P3, zaB1h, hmB);

                float bv[16];
                {
                    const float4* bp = (const float4*)(sB1p + c * 32 + gh * 16);
                    float4 b0 = bp[0], b1v = bp[1], b2v = bp[2], b3 = bp[3];
                    bv[0]=b0.x; bv[1]=b0.y; bv[2]=b0.z; bv[3]=b0.w;
                    bv[4]=b1v.x; bv[5]=b1v.y; bv[6]=b1v.z; bv[7]=b1v.w;
                    bv[8]=b2v.x; bv[9]=b2v.y; bv[10]=b2v.z; bv[11]=b2v.w;
                    bv[12]=b3.x; bv[13]=b3.y; bv[14]=b3.z; bv[15]=b3.w;
                }
                float rvA[16], rvB[16]; u32 mbA = 0, mbB = 0;
                #pragma unroll
                for (int r = 0; r < 16; ++r) {
                    float sA = hmA[r] + bv[r];
                    float sB = hmB[r] + bv[r];
                    if (sA > 0.f) mbA |= (1u << r);
                    if (sB > 0.f) mbB |= (1u << r);
                    rvA[r] = fmaxf(sA, 0.f);
                    rvB[r] = fmaxf(sB, 0.f);
                }
                mkb[c * 128 + ln] = (u16)mbA;
                mkb[c * 128 + 64 + ln] = (u16)mbB;

                f16x8 rfA0, rfA1, rlA0, rlA1, rfB0, rfB1, rlB0, rlB1;
                BUILD_FRAGS(rfA0, rfA1, rlA0, rlA1, rvA)
                BUILD_FRAGS(rfB0, rfB1, rlB0, rlB1, rvB)
                LOADSET4(P, (c < NCH - 1) ? (pfwd + (c + 1) * 8192) : pbwd)
                MFMA(ymA, Q0, rfA0, ymA); MFMA(ymB, Q0, rfB0, ymB);
                MFMA(ymA, Q0, rlA0, ymA); MFMA(ymB, Q0, rlB0, ymB);
                MFMA(ymA, Q2, rfA0, ymA); MFMA(ymB, Q2, rfB0, ymB);
                MFMA(ymA, Q1, rfA1, ymA); MFMA(ymB, Q1, rfB1, ymB);
                MFMA(ymA, Q1, rlA1, ymA); MFMA(ymB, Q1, rlB1, ymB);
                MFMA(ymA, Q3, rfA1, ymA); MFMA(ymB, Q3, rfB1, ymB);
            }

            // ============ G = 8*Y/||Y|| per tile — register-local ==========
            f16x8 gfA0, gfA1, glA0, glA1, gfB0, gfB1, glB0, glB1;
            {
                float yv[16], t = 0.f;
                #pragma unroll
                for (int r = 0; r < 16; ++r) {
                    float y = ymA[r]; yv[r] = y; t = fmaf(y, y, t);
                }
                t += __shfl_xor(t, 32, 64);
                float s8 = 8.0f * rsqrtf(t);
                #pragma unroll
                for (int r = 0; r < 16; ++r) yv[r] *= s8;
                BUILD_FRAGS(gfA0, gfA1, glA0, glA1, yv)
            }
            {
                float yv[16], t = 0.f;
                #pragma unroll
                for (int r = 0; r < 16; ++r) {
                    float y = ymB[r]; yv[r] = y; t = fmaf(y, y, t);
                }
                t += __shfl_xor(t, 32, 64);
                float s8 = 8.0f * rsqrtf(t);
                #pragma unroll
                for (int r = 0; r < 16; ++r) yv[r] *= s8;
                BUILD_FRAGS(gfB0, gfB1, glB0, glB1, yv)
            }

            f32x16 kmA, kmB;
            #pragma unroll
            for (int r = 0; r < 16; ++r) { kmA[r] = 0.f; kmB[r] = 0.f; }

            // ============ backward: dual-tile ==============================
            #pragma unroll 1
            for (int c = 0; c < NCH; ++c) {
                LOADSET4(Q, pbwd + c * 8192 + 4096)     // G2 weights of c
                f32x16 gmA, gmB;
                MFMA(gmA, P0, gfA0, zeros); MFMA(gmB, P0, gfB0, zeros);
                MFMA(gmA, P0, glA0, gmA);   MFMA(gmB, P0, glB0, gmB);
                MFMA(gmA, P2, gfA0, gmA);   MFMA(gmB, P2, gfB0, gmB);
                MFMA(gmA, P1, gfA1, gmA);   MFMA(gmB, P1, gfB1, gmB);
                MFMA(gmA, P1, glA1, gmA);   MFMA(gmB, P1, glB1, gmB);
                MFMA(gmA, P3, gfA1, gmA);   MFMA(gmB, P3, gfB1, gmB);

                u32 mbA = mkb[c * 128 + ln];
                u32 mbB = mkb[c * 128 + 64 + ln];
                float mvA[16], mvB[16];
                #pragma unroll
                for (int r = 0; r < 16; ++r) {
                    mvA[r] = (mbA & (1u << r)) ? -gmA[r] : 0.f;
                    mvB[r] = (mbB & (1u << r)) ? -gmB[r] : 0.f;
                }

                f16x8 mfA0, mfA1, mlA0, mlA1, mfB0, mfB1, mlB0, mlB1;
                BUILD_FRAGS(mfA0, mfA1, mlA0, mlA1, mvA)
                BUILD_FRAGS(mfB0, mfB1, mlB0, mlB1, mvB)
                LOADSET4(P, (c < NCH - 1) ? (pbwd + (c + 1) * 8192) : pfwd)
                MFMA(kmA, Q0, mfA0, kmA); MFMA(kmB, Q0, mfB0, kmB);
                MFMA(kmA, Q0, mlA0, kmA); MFMA(kmB, Q0, mlB0, kmB);
                MFMA(kmA, Q2, mfA0, kmA); MFMA(kmB, Q2, mfB0, kmB);
                MFMA(kmA, Q1, mfA1, kmA); MFMA(kmB, Q1, mfB1, kmB);
                MFMA(kmA, Q1, mlA1, kmA); MFMA(kmB, Q1, mlB1, kmB);
                MFMA(kmA, Q3, mfA1, kmA); MFMA(kmB, Q3, mfB1, kmB);
            }

            // ============ RK4 bookkeeping + fused za rebuild ==============
            if (sub < 3) {
                float aw = (sub == 0) ? 1.f : 2.f;
                float cw = (sub == 2) ? 0.1f : 0.05f;
                float vzA[16], vzB[16];
                #pragma unroll
                for (int r = 0; r < 16; ++r) {
                    float ka = kmA[r], kb = kmB[r];
                    accA[r] += aw * ka;           accB[r] += aw * kb;
                    vzA[r] = fmaf(cw, ka, zbA[r]); vzB[r] = fmaf(cw, kb, zbB[r]);
                }
                BUILD_FRAGS(zaA0h, zaA1h, zaA0l, zaA1l, vzA)
                BUILD_FRAGS(zaB0h, zaB1h, zaB0l, zaB1l, vzB)
            } else {
                #pragma unroll
                for (int r = 0; r < 16; ++r) { accA[r] += kmA[r]; accB[r] += kmB[r]; }
            }
        } // sub

        #pragma unroll
        for (int r = 0; r < 16; ++r) {
            zbA[r] = fmaf(0.1f / 6.0f, accA[r], zbA[r]);
            zbB[r] = fmaf(0.1f / 6.0f, accB[r], zbB[r]);
        }
        BUILD_FRAGS(zaA0h, zaA1h, zaA0l, zaA1l, zbA)
        BUILD_FRAGS(zaB0h, zaB1h, zaB0l, zaB1l, zbB)
    } // step

    {
        float* oa = out + samp * UNITS;
        float* ob = out + (samp + 32) * UNITS;
        #pragma unroll
        for (int q = 0; q < 4; ++q) {
            float4 va, vb;
            va.x = zbA[4*q+0]; va.y = zbA[4*q+1]; va.z = zbA[4*q+2]; va.w = zbA[4*q+3];
            vb.x = zbB[4*q+0]; vb.y = zbB[4*q+1]; vb.z = zbB[4*q+2]; vb.w = zbB[4*q+3];
            *(float4*)(oa + 8 * q + 4 * gh) = va;
            *(float4*)(ob + 8 * q + 4 * gh) = vb;
        }
    }
}

extern "C" void kernel_launch(void* const* d_in, const int* in_sizes, int n_in,
                              void* d_out, int out_size, void* d_ws, size_t ws_size,
                              hipStream_t stream) {
    const float* x  = (const float*)d_in[0];
    const float* W1 = (const float*)d_in[1];
    const float* b1 = (const float*)d_in[2];
    const float* W2 = (const float*)d_in[3];
    const float* b2 = (const float*)d_in[4];
    float* out = (float*)d_out;
    f16* ws = (f16*)d_ws;   // 512 KB
    hipLaunchKernelGGL(prep_weights, dim3(128), dim3(256), 0, stream, W1, W2, ws);
    hipLaunchKernelGGL(hopfield_mfma10, dim3(NBLK), dim3(TPB), 0, stream,
                       x, b1, b2, ws, out);
}

// Round 20
// 3643.316 us; speedup vs baseline: 1.1578x; 1.0657x over previous
//
#include <hip/hip_runtime.h>

typedef _Float16 f16;
typedef __attribute__((ext_vector_type(8))) _Float16 f16x8;
typedef __attribute__((ext_vector_type(16))) float f32x16;
typedef __attribute__((ext_vector_type(4))) unsigned int u32x4;
typedef unsigned int u32;
typedef unsigned short u16;

#define UNITS 32
#define HID   1024
#define NCH   32      // 32 chunks of 32 j
#define TPB   256     // 4 waves
#define WPB   4
#define SPB   256     // samples per block: 4 waves x 64 (2 tiles of 32)
#define NBLK  512
#define BWDOFF 262144

static_assert(NBLK * SPB == 131072, "grid covers batch");

// d_ws (512 KB): two regions (FWD @0, BWD @256KB), each
// [c:32][load:8][lane:64][16B], load = slice*2 + frag.
// FWD slices: 0/1 = W1^T hi/lo (A of H^T=W1^T@Z^T), 2/3 = W2^T hi/lo (A of Y^T)
// BWD slices: 0/1 = W2  hi/lo (A of GR^T=W2@G^T),   2/3 = W1  hi/lo (A of K^T)
// lo residuals UNSCALED: lo = f16(v - hi); all 3 split MFMAs share one C.
//
// k-order permutation sigma: actual k -> (frag, lane-half, reg) =
// ((rr>>3), (k>>2)&1, rr&7) with rr=(k&3)+4*(k>>3). This makes the MFMA
// C-output row order (SROW) EQUAL the B-fragment slot order, so activation
// fragments pack pairwise in-register with NO permlane swaps.
__global__ void prep_weights(const float* __restrict__ W1,
                             const float* __restrict__ W2,
                             f16* __restrict__ ws) {
    int idx = blockIdx.x * 256 + threadIdx.x;   // (c, jl, u)
    int c = idx >> 10, rem = idx & 1023;
    int jl = rem >> 5, u = rem & 31;
    int j = c * 32 + jl;
    float w1 = W1[u * HID + j];
    f16 h1 = (f16)w1;
    f16 l1 = (f16)(w1 - (float)h1);
    float w2 = W2[j * UNITS + u];
    f16 h2 = (f16)w2;
    f16 l2 = (f16)(w2 - (float)h2);
    char* p = (char*)ws;
    auto off = [&](int region, int slice, int row, int k) {
        int ghc = (k >> 2) & 1;                 // consuming lane half
        int rr  = (k & 3) + 4 * (k >> 3);       // 0..15
        int ks  = rr >> 3;                      // frag (0/1)
        int i   = rr & 7;                       // reg within frag
        int lane = row + ghc * 32;
        return region + c * 8192 + (slice * 2 + ks) * 1024 + lane * 16 + i * 2;
    };
    *(f16*)(p + off(0, 0, jl, u))      = h1;    // k = u
    *(f16*)(p + off(0, 1, jl, u))      = l1;
    *(f16*)(p + off(0, 2, u, jl))      = h2;    // k = jl
    *(f16*)(p + off(0, 3, u, jl))      = l2;
    *(f16*)(p + off(BWDOFF, 0, jl, u)) = h2;    // k = u
    *(f16*)(p + off(BWDOFF, 1, jl, u)) = l2;
    *(f16*)(p + off(BWDOFF, 2, u, jl)) = h1;    // k = jl
    *(f16*)(p + off(BWDOFF, 3, u, jl)) = l1;
}

// r = v - f32(f16 half of h): single v_fma_mix_f32 (f16 source, f32 math)
__device__ __forceinline__ float fmix_lo(u32 h, float v, float fone) {
    float r;
    asm("v_fma_mix_f32 %0, -%1, %2, %3 op_sel_hi:[1,0,0]"
        : "=v"(r) : "v"(h), "v"(fone), "v"(v));
    return r;
}
__device__ __forceinline__ float fmix_hi(u32 h, float v, float fone) {
    float r;
    asm("v_fma_mix_f32 %0, -%1, %2, %3 op_sel:[1,0,0] op_sel_hi:[1,0,0]"
        : "=v"(r) : "v"(h), "v"(fone), "v"(v));
    return r;
}

// 4 direct global 16B loads (half chunk) into named reg set S (ping-pong).
#define LOADSET4(S, base) {                                               \
    const char* p_ = (base);                                              \
    S##0 = *(const f16x8*)(p_);                                           \
    S##1 = *(const f16x8*)(p_ + 1024);                                    \
    S##2 = *(const f16x8*)(p_ + 2048);                                    \
    S##3 = *(const f16x8*)(p_ + 3072); }

// vals[r] (own sample s32, row SROW(r)) -> B-frags. With the sigma-permuted
// weights, slot order == r order: straight pairwise packs, NO permlane.
#define BUILD_FRAGS(F0, F1, L0, L1, V) {                                  \
    u32 owh[8], owl[8];                                                   \
    _Pragma("unroll")                                                     \
    for (int i_ = 0; i_ < 8; ++i_) {                                      \
        float v0_ = (V)[2*i_], v1_ = (V)[2*i_ + 1];                       \
        auto hp_ = __builtin_amdgcn_cvt_pkrtz(v0_, v1_);                  \
        owh[i_] = __builtin_bit_cast(u32, hp_);                           \
        float r0_ = fmix_lo(owh[i_], v0_, fone);                          \
        float r1_ = fmix_hi(owh[i_], v1_, fone);                          \
        auto lp_ = __builtin_amdgcn_cvt_pkrtz(r0_, r1_);                  \
        owl[i_] = __builtin_bit_cast(u32, lp_);                           \
    }                                                                     \
    F0 = __builtin_bit_cast(f16x8, (u32x4){owh[0], owh[1], owh[2], owh[3]}); \
    F1 = __builtin_bit_cast(f16x8, (u32x4){owh[4], owh[5], owh[6], owh[7]}); \
    L0 = __builtin_bit_cast(f16x8, (u32x4){owl[0], owl[1], owl[2], owl[3]}); \
    L1 = __builtin_bit_cast(f16x8, (u32x4){owl[4], owl[5], owl[6], owl[7]}); }

#define MFMA(d, a, b, c) d = __builtin_amdgcn_mfma_f32_32x32x16_f16(a, b, c, 0, 0, 0)

__global__ __launch_bounds__(TPB, 2)
__attribute__((amdgpu_waves_per_eu(2, 2)))
void hopfield_mfma11(const float* __restrict__ x,
                     const float* __restrict__ b1,
                     const float* __restrict__ b2,
                     const f16* __restrict__ ws,
                     float* __restrict__ out) {
    __shared__ __align__(16) float sB1p[HID];   // 4 KB, SROW-permuted bias
    __shared__ __align__(16) float sB2p[UNITS];
    __shared__ u16 sMsk[WPB][NCH * 128];        // 32 KB relu masks (2 tiles/wave)

    const int tid = threadIdx.x;
    const int wv = tid >> 6, ln = tid & 63;
    const int s32 = ln & 31, gh = ln >> 5;

    for (int i = tid; i < HID; i += TPB) {
        int c = i >> 5, g_ = (i >> 4) & 1, r = i & 15;
        sB1p[i] = b1[c * 32 + ((r & 3) + ((r >> 2) << 3) + (g_ << 2))];
    }
    if (tid < UNITS) {
        int g_ = (tid >> 4) & 1, r = tid & 15;
        sB2p[tid] = b2[(r & 3) + ((r >> 2) << 3) + (g_ << 2)];
    }
    __syncthreads();          // the only block-wide barrier

    u16* mkb = &sMsk[wv][0];
    const float fone = 1.0f;

    // wave owns 64 samples: tile A = base..base+31, tile B = +32
    const long samp = (long)blockIdx.x * SPB + wv * 64 + s32;
    float zbA[16], zbB[16], accA[16], accB[16];
    {
        const float* xa = x + samp * UNITS;
        const float* xb = x + (samp + 32) * UNITS;
        #pragma unroll
        for (int q = 0; q < 4; ++q) {
            float4 va = *(const float4*)(xa + 8 * q + 4 * gh);
            float4 vb = *(const float4*)(xb + 8 * q + 4 * gh);
            zbA[4*q+0] = va.x; zbA[4*q+1] = va.y; zbA[4*q+2] = va.z; zbA[4*q+3] = va.w;
            zbB[4*q+0] = vb.x; zbB[4*q+1] = vb.y; zbB[4*q+2] = vb.z; zbB[4*q+3] = vb.w;
        }
    }

    f32x16 zeros;
    #pragma unroll
    for (int r = 0; r < 16; ++r) zeros[r] = 0.f;

    const char* pfwd = (const char*)ws + (size_t)ln * 16;
    const char* pbwd = pfwd + BWDOFF;

    f16x8 P0, P1, P2, P3;     // GEMM-1 weights of current chunk
    f16x8 Q0, Q1, Q2, Q3;     // GEMM-2 weights of current chunk
    LOADSET4(P, pfwd)         // prologue: fwd chunk 0 G1 in flight

    f16x8 zaA0h, zaA1h, zaA0l, zaA1l;
    f16x8 zaB0h, zaB1h, zaB0l, zaB1l;
    BUILD_FRAGS(zaA0h, zaA1h, zaA0l, zaA1l, zbA)
    BUILD_FRAGS(zaB0h, zaB1h, zaB0l, zaB1l, zbB)

    #pragma unroll 1
    for (int step = 0; step < 10; ++step) {
        #pragma unroll
        for (int r = 0; r < 16; ++r) { accA[r] = 0.f; accB[r] = 0.f; }

        #pragma unroll 1
        for (int sub = 0; sub < 4; ++sub) {
            f32x16 ymA, ymB;
            {   // Y^T accumulator init with b2 (SROW order)
                const float4* bp = (const float4*)(sB2p + gh * 16);
                float4 v0 = bp[0], v1 = bp[1], v2 = bp[2], v3 = bp[3];
                ymA[0]=v0.x; ymA[1]=v0.y; ymA[2]=v0.z; ymA[3]=v0.w;
                ymA[4]=v1.x; ymA[5]=v1.y; ymA[6]=v1.z; ymA[7]=v1.w;
                ymA[8]=v2.x; ymA[9]=v2.y; ymA[10]=v2.z; ymA[11]=v2.w;
                ymA[12]=v3.x; ymA[13]=v3.y; ymA[14]=v3.z; ymA[15]=v3.w;
                #pragma unroll
                for (int r = 0; r < 16; ++r) ymB[r] = ymA[r];
            }

            // ============ forward: dual-tile, interleaved MFMA chains ======
            #pragma unroll 1
            for (int c = 0; c < NCH; ++c) {
                LOADSET4(Q, pfwd + c * 8192 + 4096)     // G2 weights of c
                f32x16 hmA, hmB;
                MFMA(hmA, P0, zaA0h, zeros); MFMA(hmB, P0, zaB0h, zeros);
                MFMA(hmA, P0, zaA0l, hmA);   MFMA(hmB, P0, zaB0l, hmB);
                MFMA(hmA, P2, zaA0h, hmA);   MFMA(hmB, P2, zaB0h, hmB);
                MFMA(hmA, P1, zaA1h, hmA);   MFMA(hmB, P1, zaB1h, hmB);
                MFMA(hmA, P1, zaA1l, hmA);   MFMA(hmB, P1, zaB1l, hmB);
                MFMA(hmA, P3, zaA1h, hmA);   MFMA(hmB, P3, zaB1h, hmB);

                float bv[16];
                {
                    const float4* bp = (const float4*)(sB1p + c * 32 + gh * 16);
                    float4 b0 = bp[0], b1v = bp[1], b2v = bp[2], b3 = bp[3];
                    bv[0]=b0.x; bv[1]=b0.y; bv[2]=b0.z; bv[3]=b0.w;
                    bv[4]=b1v.x; bv[5]=b1v.y; bv[6]=b1v.z; bv[7]=b1v.w;
                    bv[8]=b2v.x; bv[9]=b2v.y; bv[10]=b2v.z; bv[11]=b2v.w;
                    bv[12]=b3.x; bv[13]=b3.y; bv[14]=b3.z; bv[15]=b3.w;
                }
                float rvA[16], rvB[16]; u32 mbA = 0, mbB = 0;
                #pragma unroll
                for (int r = 0; r < 16; ++r) {
                    float sA = hmA[r] + bv[r];
                    float sB = hmB[r] + bv[r];
                    if (sA > 0.f) mbA |= (1u << r);
                    if (sB > 0.f) mbB |= (1u << r);
                    rvA[r] = fmaxf(sA, 0.f);
                    rvB[r] = fmaxf(sB, 0.f);
                }
                mkb[c * 128 + ln] = (u16)mbA;
                mkb[c * 128 + 64 + ln] = (u16)mbB;

                f16x8 rfA0, rfA1, rlA0, rlA1, rfB0, rfB1, rlB0, rlB1;
                BUILD_FRAGS(rfA0, rfA1, rlA0, rlA1, rvA)
                BUILD_FRAGS(rfB0, rfB1, rlB0, rlB1, rvB)
                LOADSET4(P, (c < NCH - 1) ? (pfwd + (c + 1) * 8192) : pbwd)
                MFMA(ymA, Q0, rfA0, ymA); MFMA(ymB, Q0, rfB0, ymB);
                MFMA(ymA, Q0, rlA0, ymA); MFMA(ymB, Q0, rlB0, ymB);
                MFMA(ymA, Q2, rfA0, ymA); MFMA(ymB, Q2, rfB0, ymB);
                MFMA(ymA, Q1, rfA1, ymA); MFMA(ymB, Q1, rfB1, ymB);
                MFMA(ymA, Q1, rlA1, ymA); MFMA(ymB, Q1, rlB1, ymB);
                MFMA(ymA, Q3, rfA1, ymA); MFMA(ymB, Q3, rfB1, ymB);
            }

            // ============ G = 8*Y/||Y|| per tile — register-local ==========
            f16x8 gfA0, gfA1, glA0, glA1, gfB0, gfB1, glB0, glB1;
            {
                float yv[16], t = 0.f;
                #pragma unroll
                for (int r = 0; r < 16; ++r) {
                    float y = ymA[r]; yv[r] = y; t = fmaf(y, y, t);
                }
                t += __shfl_xor(t, 32, 64);
                float s8 = 8.0f * rsqrtf(t);
                #pragma unroll
                for (int r = 0; r < 16; ++r) yv[r] *= s8;
                BUILD_FRAGS(gfA0, gfA1, glA0, glA1, yv)
            }
            {
                float yv[16], t = 0.f;
                #pragma unroll
                for (int r = 0; r < 16; ++r) {
                    float y = ymB[r]; yv[r] = y; t = fmaf(y, y, t);
                }
                t += __shfl_xor(t, 32, 64);
                float s8 = 8.0f * rsqrtf(t);
                #pragma unroll
                for (int r = 0; r < 16; ++r) yv[r] *= s8;
                BUILD_FRAGS(gfB0, gfB1, glB0, glB1, yv)
            }

            f32x16 kmA, kmB;
            #pragma unroll
            for (int r = 0; r < 16; ++r) { kmA[r] = 0.f; kmB[r] = 0.f; }

            // ============ backward: dual-tile ==============================
            #pragma unroll 1
            for (int c = 0; c < NCH; ++c) {
                LOADSET4(Q, pbwd + c * 8192 + 4096)     // G2 weights of c
                f32x16 gmA, gmB;
                MFMA(gmA, P0, gfA0, zeros); MFMA(gmB, P0, gfB0, zeros);
                MFMA(gmA, P0, glA0, gmA);   MFMA(gmB, P0, glB0, gmB);
                MFMA(gmA, P2, gfA0, gmA);   MFMA(gmB, P2, gfB0, gmB);
                MFMA(gmA, P1, gfA1, gmA);   MFMA(gmB, P1, gfB1, gmB);
                MFMA(gmA, P1, glA1, gmA);   MFMA(gmB, P1, glB1, gmB);
                MFMA(gmA, P3, gfA1, gmA);   MFMA(gmB, P3, gfB1, gmB);

                u32 mbA = mkb[c * 128 + ln];
                u32 mbB = mkb[c * 128 + 64 + ln];
                float mvA[16], mvB[16];
                #pragma unroll
                for (int r = 0; r < 16; ++r) {
                    mvA[r] = (mbA & (1u << r)) ? -gmA[r] : 0.f;
                    mvB[r] = (mbB & (1u << r)) ? -gmB[r] : 0.f;
                }

                f16x8 mfA0, mfA1, mlA0, mlA1, mfB0, mfB1, mlB0, mlB1;
                BUILD_FRAGS(mfA0, mfA1, mlA0, mlA1, mvA)
                BUILD_FRAGS(mfB0, mfB1, mlB0, mlB1, mvB)
                LOADSET4(P, (c < NCH - 1) ? (pbwd + (c + 1) * 8192) : pfwd)
                MFMA(kmA, Q0, mfA0, kmA); MFMA(kmB, Q0, mfB0, kmB);
                MFMA(kmA, Q0, mlA0, kmA); MFMA(kmB, Q0, mlB0, kmB);
                MFMA(kmA, Q2, mfA0, kmA); MFMA(kmB, Q2, mfB0, kmB);
                MFMA(kmA, Q1, mfA1, kmA); MFMA(kmB, Q1, mfB1, kmB);
                MFMA(kmA, Q1, mlA1, kmA); MFMA(kmB, Q1, mlB1, kmB);
                MFMA(kmA, Q3, mfA1, kmA); MFMA(kmB, Q3, mfB1, kmB);
            }

            // ============ RK4 bookkeeping + fused za rebuild ==============
            if (sub < 3) {
                float aw = (sub == 0) ? 1.f : 2.f;
                float cw = (sub == 2) ? 0.1f : 0.05f;
                float vzA[16], vzB[16];
                #pragma unroll
                for (int r = 0; r < 16; ++r) {
                    float ka = kmA[r], kb = kmB[r];
                    accA[r] += aw * ka;           accB[r] += aw * kb;
                    vzA[r] = fmaf(cw, ka, zbA[r]); vzB[r] = fmaf(cw, kb, zbB[r]);
                }
                BUILD_FRAGS(zaA0h, zaA1h, zaA0l, zaA1l, vzA)
                BUILD_FRAGS(zaB0h, zaB1h, zaB0l, zaB1l, vzB)
            } else {
                #pragma unroll
                for (int r = 0; r < 16; ++r) { accA[r] += kmA[r]; accB[r] += kmB[r]; }
            }
        } // sub

        #pragma unroll
        for (int r = 0; r < 16; ++r) {
            zbA[r] = fmaf(0.1f / 6.0f, accA[r], zbA[r]);
            zbB[r] = fmaf(0.1f / 6.0f, accB[r], zbB[r]);
        }
        BUILD_FRAGS(zaA0h, zaA1h, zaA0l, zaA1l, zbA)
        BUILD_FRAGS(zaB0h, zaB1h, zaB0l, zaB1l, zbB)
    } // step

    {
        float* oa = out + samp * UNITS;
        float* ob = out + (samp + 32) * UNITS;
        #pragma unroll
        for (int q = 0; q < 4; ++q) {
            float4 va, vb;
            va.x = zbA[4*q+0]; va.y = zbA[4*q+1]; va.z = zbA[4*q+2]; va.w = zbA[4*q+3];
            vb.x = zbB[4*q+0]; vb.y = zbB[4*q+1]; vb.z = zbB[4*q+2]; vb.w = zbB[4*q+3];
            *(float4*)(oa + 8 * q + 4 * gh) = va;
            *(float4*)(ob + 8 * q + 4 * gh) = vb;
        }
    }
}

extern "C" void kernel_launch(void* const* d_in, const int* in_sizes, int n_in,
                              void* d_out, int out_size, void* d_ws, size_t ws_size,
                              hipStream_t stream) {
    const float* x  = (const float*)d_in[0];
    const float* W1 = (const float*)d_in[1];
    const float* b1 = (const float*)d_in[2];
    const float* W2 = (const float*)d_in[3];
    const float* b2 = (const float*)d_in[4];
    float* out = (float*)d_out;
    f16* ws = (f16*)d_ws;   // 512 KB
    hipLaunchKernelGGL(prep_weights, dim3(128), dim3(256), 0, stream, W1, W2, ws);
    hipLaunchKernelGGL(hopfield_mfma11, dim3(NBLK), dim3(TPB), 0, stream,
                       x, b1, b2, ws, out);
}